// Round 1
// baseline (298.473 us; speedup 1.0000x reference)
//
#include <hip/hip_runtime.h>

// Problem constants (from reference)
#define IMG_W 640
#define IMG_H 480
#define BATCH 32
#define HWSZ (IMG_H * IMG_W)          // 307200
#define CHWSZ (3 * HWSZ)              // 921600
#define NPIX (BATCH * HWSZ)           // 9830400

// No LDS staging: the tap working set (2 rows x 3ch = 15 KB) is L1-resident,
// and the whole input (~275 MB) is L3-resident in steady state (measured:
// replay dispatches show hbm_bytes ~0.25 MB). Direct global taps through
// L1/L2 remove the staging loads, the 1.5x rgb_left re-read, and both
// per-block barriers that serialized the old 640-thread blocks.
//
// Thread -> 4 consecutive x pixels of one row: float4 streaming loads for
// depth + rgb_right, row-y math amortized per thread, 4 independent
// bilinear-tap chains (12 gather loads each) for ILP.

#define TPB 256
#define QPR (IMG_W / 4)            // 160 quads per row
#define QPI (IMG_H * QPR)          // 76800 quads per image
#define BPI (QPI / TPB)            // 300 blocks per image (exact)
#define NBLOCKS (BATCH * BPI)      // 9600

__global__ __launch_bounds__(TPB, 4) void photo_main(
    const float* __restrict__ rgb_right,
    const float* __restrict__ rgb_left,
    const float* __restrict__ depth,
    float* __restrict__ partials)
{
    // bb is block-uniform (BPI divides blocks-per-image exactly) -> SALU
    const int bb   = blockIdx.x / BPI;
    const int rblk = blockIdx.x - bb * BPI;
    const int q    = rblk * TPB + threadIdx.x;   // quad index within image
    const int v    = q / QPR;                    // row (const-div -> magic mul)
    const int qx   = q - v * QPR;
    const int x0   = qx * 4;

    const float* __restrict__ Lb = rgb_left + bb * CHWSZ;

    // Row-level y math (V_proj == v exactly in the reference's math):
    // y = 480*v/479 - 0.5, constant across the thread's 4 pixels.
    const float yrow = (480.0f * (float)v) / 479.0f - 0.5f;
    const int y0i = (int)floorf(yrow);
    const float wy1 = yrow - (float)y0i;
    const float wy0 = 1.0f - wy1;
    const float wy0m = (y0i >= 0) ? wy0 : 0.0f;
    const float wy1m = (y0i + 1 <= IMG_H - 1) ? wy1 : 0.0f;
    const int r0 = max(y0i, 0);
    const int r1 = min(y0i + 1, IMG_H - 1);
    const float* __restrict__ row0 = Lb + r0 * IMG_W;   // R plane; +HWSZ/G, +2*HWSZ/B
    const float* __restrict__ row1 = Lb + r1 * IMG_W;

    const int pbase = bb * HWSZ + v * IMG_W + x0;    // fits int32 (<2^25)
    const int cbase = bb * CHWSZ + v * IMG_W + x0;   // fits int32 (<2^25)

    // Vectorized streaming loads: 16 B/lane, fully coalesced.
    const float4 d4 = *(const float4*)(depth + pbase);
    const float4 R0 = *(const float4*)(rgb_right + cbase);
    const float4 R1 = *(const float4*)(rgb_right + cbase + HWSZ);
    const float4 R2 = *(const float4*)(rgb_right + cbase + 2 * HWSZ);

    const float dv[4] = {d4.x, d4.y, d4.z, d4.w};
    const float rv[4] = {R0.x, R0.y, R0.z, R0.w};
    const float gv[4] = {R1.x, R1.y, R1.z, R1.w};
    const float bv[4] = {R2.x, R2.y, R2.z, R2.w};

    float acc = 0.0f;

#pragma unroll
    for (int j = 0; j < 4; ++j) {   // 4 independent chains; static indexing only
        const float dd = dv[j];
        const float uf = (float)(x0 + j);

        // x math: U_proj = u + 80/d (algebraic simplification of
        // FU*(d*Xc+B)/Z + CU with Z=d); x = U_proj*(640/639) - 0.5.
        const float rz = __builtin_amdgcn_rcpf(fmaxf(dd, 0.001f));
        const float Up = fmaf(80.0f, rz, uf);
        const bool valid = (Up <= 639.0f);       // Up >= 1 always, so un >= -1
        const float x = fmaf(Up, 640.0f / 639.0f, -0.5f);
        const float x0f = floorf(x);
        const float wx1 = x - x0f;
        const float wx0 = 1.0f - wx1;
        const int xi = (int)x0f;
        const bool vx1 = (xi < IMG_W - 1);
        const int e0 = min(max(xi, 0), IMG_W - 1);
        const int e1 = min(xi + 1, IMG_W - 1);

        const float vm  = valid ? 1.0f : 0.0f;
        const float v1m = (valid && vx1) ? 1.0f : 0.0f;
        const float w00 = wy0m * wx0 * vm;
        const float w01 = wy0m * wx1 * v1m;
        const float w10 = wy1m * wx0 * vm;
        const float w11 = wy1m * wx1 * v1m;

        // 12 direct gather loads (lane-consecutive addresses -> coalesced,
        // L1/L2-served). All independent -> deep MLP across the 4-px unroll.
        const float t00r = row0[e0],            t01r = row0[e1];
        const float t10r = row1[e0],            t11r = row1[e1];
        const float t00g = row0[e0 + HWSZ],     t01g = row0[e1 + HWSZ];
        const float t10g = row1[e0 + HWSZ],     t11g = row1[e1 + HWSZ];
        const float t00b = row0[e0 + 2*HWSZ],   t01b = row0[e1 + 2*HWSZ];
        const float t10b = row1[e0 + 2*HWSZ],   t11b = row1[e1 + 2*HWSZ];

        const float wa = w00*t00r + w01*t01r + w10*t10r + w11*t11r;
        const float wb = w00*t00g + w01*t01g + w10*t10g + w11*t11g;
        const float wc = w00*t00b + w01*t01b + w10*t10b + w11*t11b;

        const float wsum = wa + wb + wc;
        const float diff = fabsf(wa - rv[j]) + fabsf(wb - gv[j]) + fabsf(wc - bv[j]);

        // rgb_left channel-sum > 0 holds w.p. ~1 for uniform(0,255) inputs.
        acc += (wsum > 0.0f) ? diff : 0.0f;
    }

    // wave(64) shuffle reduce, then LDS across 4 waves
    for (int off = 32; off > 0; off >>= 1)
        acc += __shfl_down(acc, off, 64);

    __shared__ float red[TPB / 64];
    const int lane = threadIdx.x & 63;
    const int wave = threadIdx.x >> 6;
    if (lane == 0) red[wave] = acc;
    __syncthreads();
    if (threadIdx.x == 0) {
        float s = 0.0f;
#pragma unroll
        for (int w = 0; w < TPB / 64; ++w) s += red[w];
        partials[blockIdx.x] = s;
    }
}

__global__ __launch_bounds__(1024) void photo_finish(
    const float* __restrict__ partials,
    float* __restrict__ out,
    int nb)
{
    double s = 0.0;
    for (int i = threadIdx.x; i < nb; i += blockDim.x)
        s += (double)partials[i];

    for (int off = 32; off > 0; off >>= 1)
        s += __shfl_down(s, off, 64);

    __shared__ double lds[16];
    const int lane = threadIdx.x & 63;
    const int wave = threadIdx.x >> 6;
    if (lane == 0) lds[wave] = s;
    __syncthreads();
    if (threadIdx.x == 0) {
        double tt = 0.0;
#pragma unroll
        for (int w = 0; w < 16; ++w) tt += lds[w];
        out[0] = (float)(tt / (double)NPIX);
    }
}

extern "C" void kernel_launch(void* const* d_in, const int* in_sizes, int n_in,
                              void* d_out, int out_size, void* d_ws, size_t ws_size,
                              hipStream_t stream) {
    const float* rgb_right = (const float*)d_in[0];
    const float* rgb_left  = (const float*)d_in[1];
    const float* depth     = (const float*)d_in[2];
    float* partials = (float*)d_ws;
    float* out = (float*)d_out;

    photo_main<<<NBLOCKS, TPB, 0, stream>>>(rgb_right, rgb_left, depth, partials);
    photo_finish<<<1, 1024, 0, stream>>>(partials, out, NBLOCKS);
}

// Round 2
// 297.847 us; speedup vs baseline: 1.0021x; 1.0021x over previous
//
#include <hip/hip_runtime.h>

// Problem constants (from reference)
#define IMG_W 640
#define IMG_H 480
#define BATCH 32
#define HWSZ (IMG_H * IMG_W)          // 307200
#define CHWSZ (3 * HWSZ)              // 921600
#define NPIX (BATCH * HWSZ)           // 9830400

// HBM-streaming kernel (inputs re-poisoned per iteration -> cold caches,
// FETCH ~172 MB/dispatch). Floor = 172 MB / 6.3 TB/s ~ 27 us. Previous
// versions ran at 1.4-1.5 TB/s because the compiler (VGPR=20/36) consumed
// every load immediately -> <1 cache line in flight per wave -> miss
// serialization. This version forces MLP at the source level:
//   phase 0: issue 4 streaming float4 loads (depth + 3x rgb_right)
//   phase 1: wait on depth ONLY; compute all 4 pixels' addrs + weights
//   phase 2: issue all 48 rgb_left tap loads into registers (static idx)
//   phase 3: consume everything (incl. rgb_right fields), accumulate
// Per-pixel arithmetic and accumulation order identical to the previous
// passing kernel -> bitwise-identical partials (absmax 0).

#define TPB 256
#define QPR (IMG_W / 4)            // 160 quads per row
#define QPI (IMG_H * QPR)          // 76800 quads per image
#define BPI (QPI / TPB)            // 300 blocks per image (exact)
#define NBLOCKS (BATCH * BPI)      // 9600

__global__ __launch_bounds__(TPB, 4) void photo_main(
    const float* __restrict__ rgb_right,
    const float* __restrict__ rgb_left,
    const float* __restrict__ depth,
    float* __restrict__ partials)
{
    // bb is block-uniform (BPI divides blocks-per-image exactly) -> SALU
    const int bb   = blockIdx.x / BPI;
    const int rblk = blockIdx.x - bb * BPI;
    const int q    = rblk * TPB + threadIdx.x;   // quad index within image
    const int v    = q / QPR;                    // row (const-div -> magic mul)
    const int qx   = q - v * QPR;
    const int x0   = qx * 4;

    const int pbase = bb * HWSZ + v * IMG_W + x0;    // fits int32
    const int cbase = bb * CHWSZ + v * IMG_W + x0;   // fits int32

    // ---- phase 0: issue all streaming loads (4 outstanding) ----
    const float4 d4 = *(const float4*)(depth + pbase);
    const float4 R0 = *(const float4*)(rgb_right + cbase);
    const float4 R1 = *(const float4*)(rgb_right + cbase + HWSZ);
    const float4 R2 = *(const float4*)(rgb_right + cbase + 2 * HWSZ);

    // ---- row-level y math (no memory; V_proj == v exactly) ----
    const float yrow = (480.0f * (float)v) / 479.0f - 0.5f;
    const int y0i = (int)floorf(yrow);
    const float wy1 = yrow - (float)y0i;
    const float wy0 = 1.0f - wy1;
    const float wy0m = (y0i >= 0) ? wy0 : 0.0f;
    const float wy1m = (y0i + 1 <= IMG_H - 1) ? wy1 : 0.0f;
    const int r0 = max(y0i, 0);
    const int r1 = min(y0i + 1, IMG_H - 1);
    const float* __restrict__ Lb = rgb_left + bb * CHWSZ;
    const float* __restrict__ row0 = Lb + r0 * IMG_W;   // R plane; +HWSZ, +2*HWSZ
    const float* __restrict__ row1 = Lb + r1 * IMG_W;

    // ---- phase 1: addresses + weights for all 4 px (waits on depth only;
    // rgb_right loads stay in flight) ----
    const float dv[4] = {d4.x, d4.y, d4.z, d4.w};
    int e0[4], e1[4];
    float w00[4], w01[4], w10[4], w11[4];
#pragma unroll
    for (int j = 0; j < 4; ++j) {
        const float dd = dv[j];
        const float uf = (float)(x0 + j);
        // U_proj = u + 80/d (FU*(d*Xc+B)/Z + CU with Z=d); x = U*(640/639)-0.5
        const float rz = __builtin_amdgcn_rcpf(fmaxf(dd, 0.001f));
        const float Up = fmaf(80.0f, rz, uf);
        const bool valid = (Up <= 639.0f);       // Up >= 1 always
        const float x = fmaf(Up, 640.0f / 639.0f, -0.5f);
        const float x0f = floorf(x);
        const float wx1 = x - x0f;
        const float wx0 = 1.0f - wx1;
        const int xi = (int)x0f;
        const bool vx1 = (xi < IMG_W - 1);
        e0[j] = min(max(xi, 0), IMG_W - 1);
        e1[j] = min(xi + 1, IMG_W - 1);
        const float vm  = valid ? 1.0f : 0.0f;
        const float v1m = (valid && vx1) ? 1.0f : 0.0f;
        w00[j] = wy0m * wx0 * vm;
        w01[j] = wy0m * wx1 * v1m;
        w10[j] = wy1m * wx0 * vm;
        w11[j] = wy1m * wx1 * v1m;
    }

    // ---- phase 2: issue ALL 48 tap loads before consuming any ----
    float t00r[4], t01r[4], t10r[4], t11r[4];
    float t00g[4], t01g[4], t10g[4], t11g[4];
    float t00b[4], t01b[4], t10b[4], t11b[4];
#pragma unroll
    for (int j = 0; j < 4; ++j) {
        t00r[j] = row0[e0[j]];              t01r[j] = row0[e1[j]];
        t10r[j] = row1[e0[j]];              t11r[j] = row1[e1[j]];
        t00g[j] = row0[e0[j] + HWSZ];       t01g[j] = row0[e1[j] + HWSZ];
        t10g[j] = row1[e0[j] + HWSZ];       t11g[j] = row1[e1[j] + HWSZ];
        t00b[j] = row0[e0[j] + 2 * HWSZ];   t01b[j] = row0[e1[j] + 2 * HWSZ];
        t10b[j] = row1[e0[j] + 2 * HWSZ];   t11b[j] = row1[e1[j] + 2 * HWSZ];
    }

    // ---- phase 3: consume (single drain of all outstanding loads) ----
    const float rv[4] = {R0.x, R0.y, R0.z, R0.w};
    const float gv[4] = {R1.x, R1.y, R1.z, R1.w};
    const float bv[4] = {R2.x, R2.y, R2.z, R2.w};

    float acc = 0.0f;
#pragma unroll
    for (int j = 0; j < 4; ++j) {
        const float wa = w00[j]*t00r[j] + w01[j]*t01r[j] + w10[j]*t10r[j] + w11[j]*t11r[j];
        const float wb = w00[j]*t00g[j] + w01[j]*t01g[j] + w10[j]*t10g[j] + w11[j]*t11g[j];
        const float wc = w00[j]*t00b[j] + w01[j]*t01b[j] + w10[j]*t10b[j] + w11[j]*t11b[j];
        const float wsum = wa + wb + wc;
        const float diff = fabsf(wa - rv[j]) + fabsf(wb - gv[j]) + fabsf(wc - bv[j]);
        // rgb_left channel-sum > 0 holds w.p. ~1 for uniform(0,255) inputs.
        acc += (wsum > 0.0f) ? diff : 0.0f;
    }

    // wave(64) shuffle reduce, then LDS across 4 waves
    for (int off = 32; off > 0; off >>= 1)
        acc += __shfl_down(acc, off, 64);

    __shared__ float red[TPB / 64];
    const int lane = threadIdx.x & 63;
    const int wave = threadIdx.x >> 6;
    if (lane == 0) red[wave] = acc;
    __syncthreads();
    if (threadIdx.x == 0) {
        float s = 0.0f;
#pragma unroll
        for (int w = 0; w < TPB / 64; ++w) s += red[w];
        partials[blockIdx.x] = s;
    }
}

__global__ __launch_bounds__(1024) void photo_finish(
    const float* __restrict__ partials,
    float* __restrict__ out,
    int nb)
{
    double s = 0.0;
    for (int i = threadIdx.x; i < nb; i += blockDim.x)
        s += (double)partials[i];

    for (int off = 32; off > 0; off >>= 1)
        s += __shfl_down(s, off, 64);

    __shared__ double lds[16];
    const int lane = threadIdx.x & 63;
    const int wave = threadIdx.x >> 6;
    if (lane == 0) lds[wave] = s;
    __syncthreads();
    if (threadIdx.x == 0) {
        double tt = 0.0;
#pragma unroll
        for (int w = 0; w < 16; ++w) tt += lds[w];
        out[0] = (float)(tt / (double)NPIX);
    }
}

extern "C" void kernel_launch(void* const* d_in, const int* in_sizes, int n_in,
                              void* d_out, int out_size, void* d_ws, size_t ws_size,
                              hipStream_t stream) {
    const float* rgb_right = (const float*)d_in[0];
    const float* rgb_left  = (const float*)d_in[1];
    const float* depth     = (const float*)d_in[2];
    float* partials = (float*)d_ws;
    float* out = (float*)d_out;

    photo_main<<<NBLOCKS, TPB, 0, stream>>>(rgb_right, rgb_left, depth, partials);
    photo_finish<<<1, 1024, 0, stream>>>(partials, out, NBLOCKS);
}

// Round 3
// 258.384 us; speedup vs baseline: 1.1552x; 1.1527x over previous
//
#include <hip/hip_runtime.h>

// Problem constants (from reference)
#define IMG_W 640
#define IMG_H 480
#define BATCH 32
#define HWSZ (IMG_H * IMG_W)          // 307200
#define CHWSZ (3 * HWSZ)              // 921600
#define NPIX (BATCH * HWSZ)           // 9830400

// TRAFFIC MODEL (rocprof, R0-R2): every dispatch carries ~240-300 MB of HBM
// WRITES -- write-backs of the harness's dirty poisoned inputs, evicted from
// L3 by our streaming reads. All three prior kernels saturated at 3.8 TB/s
// COMBINED (R+W) traffic; the fix is traffic reduction, not scheduling.
//   -> __builtin_nontemporal_load (nt bit) on ALL global input reads: misses
//      don't allocate in L2/L3, so we stop evicting dirty poison lines and
//      the write-back storm leaves our dispatch window.
//   -> nt forfeits cache reuse, so ALL reuse must be explicit: this is the
//      LDS-staging structure (R0 baseline: 108 us, 163R/241W), where taps
//      come from LDS and each global element is read <= 1.5x.
//   -> XCD-bijective block swizzle (7680 % 8 == 0): adjacent row-pairs share
//      staged rows -> same-XCD L2 captures the 1.5x staging overdraw.

#define ROWS_PER_BLK 2
#define PAIRS_PER_IMG (IMG_H / ROWS_PER_BLK)   // 240
#define NBLOCKS (BATCH * PAIRS_PER_IMG)        // 7680
#define NTHREADS IMG_W                         // 640 threads = 10 waves
#define NXCD 8
#define CHUNK (NBLOCKS / NXCD)                 // 960 (= 4 images per XCD)

__global__ __launch_bounds__(NTHREADS) void photo_main(
    const float* __restrict__ rgb_right,
    const float* __restrict__ rgb_left,
    const float* __restrict__ depth,
    float* __restrict__ partials)
{
    // XCD-aware bijective swizzle: hardware round-robins blockIdx across the
    // 8 XCDs; all bids with equal bid%8 land on one XCD and map to a
    // contiguous work chunk -> neighboring row-pairs co-resident per XCD L2.
    const int bid = blockIdx.x;
    const int wid = (bid & (NXCD - 1)) * CHUNK + (bid >> 3);
    const int bb = wid / PAIRS_PER_IMG;
    const int vpair = wid - bb * PAIRS_PER_IMG;
    const int v0 = 2 * vpair;
    const int t = threadIdx.x;          // x coordinate, 0..639

    __shared__ float4 tile[3 * IMG_W];  // [slot][x] = {r,g,b,0}
    __shared__ float red[NTHREADS / 64];

    const float* __restrict__ Lb = rgb_left + (size_t)bb * CHWSZ;

    // First source row for this pair (exact: 480*v0 < 2^24, div correctly
    // rounded, distance of y to integers >= ~1e-3 >> 1ulp).
    const float yrow0 = (480.0f * (float)v0) / 479.0f - 0.5f;
    const int y0s0 = (int)floorf(yrow0);

    // Stage 3 source rows x 640 px, packed RGBX. Non-temporal: no L2/L3
    // allocation -> no eviction of dirty poison lines. Lanes write
    // consecutive x -> ds_write_b128 conflict-free.
#pragma unroll
    for (int k = 0; k < 3; ++k) {
        const int rsrc = min(max(y0s0 + k, 0), IMG_H - 1);
        const float* src = Lb + (size_t)rsrc * IMG_W + t;
        tile[k * IMG_W + t] = make_float4(
            __builtin_nontemporal_load(src),
            __builtin_nontemporal_load(src + HWSZ),
            __builtin_nontemporal_load(src + 2 * HWSZ),
            0.0f);
    }
    __syncthreads();

    const float uf = (float)t;
    float acc = 0.0f;

#pragma unroll
    for (int i = 0; i < ROWS_PER_BLK; ++i) {
        const int v = v0 + i;

        // Row-level y math (V_proj == v exactly in the reference's math):
        // y = 480*v/479 - 0.5, constant across the row.
        const float yrow = (480.0f * (float)v) / 479.0f - 0.5f;
        const int y0i = (int)floorf(yrow);
        const float wy1 = yrow - (float)y0i;
        const float wy0 = 1.0f - wy1;
        const float wy0m = (y0i >= 0) ? wy0 : 0.0f;
        const float wy1m = (y0i + 1 <= IMG_H - 1) ? wy1 : 0.0f;
        int s0 = min(max(y0i - y0s0, 0), 1);   // == i (proven); defensive clamp
        const float4* __restrict__ row0 = &tile[s0 * IMG_W];
        const float4* __restrict__ row1 = &tile[(s0 + 1) * IMG_W];

        const size_t pbase = (size_t)bb * HWSZ + (size_t)v * IMG_W + t;
        const size_t cbase = (size_t)bb * CHWSZ + (size_t)v * IMG_W + t;
        const float dd  = __builtin_nontemporal_load(depth + pbase);
        const float Rr  = __builtin_nontemporal_load(rgb_right + cbase);
        const float Rg  = __builtin_nontemporal_load(rgb_right + cbase + HWSZ);
        const float Rb2 = __builtin_nontemporal_load(rgb_right + cbase + 2 * HWSZ);

        // x math: U_proj = u + 80/d (algebraic simplification of
        // FU*(d*Xc+B)/Z + CU with Z=d); x = U_proj*(640/639) - 0.5.
        const float rz = __builtin_amdgcn_rcpf(fmaxf(dd, 0.001f));
        const float Up = fmaf(80.0f, rz, uf);
        const bool valid = (Up <= 639.0f);     // Up >= 1 always, so un >= -1
        const float x = fmaf(Up, 640.0f / 639.0f, -0.5f);
        const float x0f = floorf(x);
        const float wx1 = x - x0f;
        const float wx0 = 1.0f - wx1;
        const int x0 = (int)x0f;
        const bool vx1 = (x0 < IMG_W - 1);
        const int e0 = min(max(x0, 0), IMG_W - 1);
        const int e1 = min(x0 + 1, IMG_W - 1);

        const float vm = valid ? 1.0f : 0.0f;
        const float v1m = (valid && vx1) ? 1.0f : 0.0f;
        const float w00 = wy0m * wx0 * vm;
        const float w01 = wy0m * wx1 * v1m;
        const float w10 = wy1m * wx0 * vm;
        const float w11 = wy1m * wx1 * v1m;

        // 4 taps, one ds_read_b128 each (RGB packed)
        const float4 t00 = row0[e0];
        const float4 t01 = row0[e1];
        const float4 t10 = row1[e0];
        const float4 t11 = row1[e1];

        const float wa = w00 * t00.x + w01 * t01.x + w10 * t10.x + w11 * t11.x;
        const float wb = w00 * t00.y + w01 * t01.y + w10 * t10.y + w11 * t11.y;
        const float wc = w00 * t00.z + w01 * t01.z + w10 * t10.z + w11 * t11.z;

        const float wsum = wa + wb + wc;
        const float diff = fabsf(wa - Rr) + fabsf(wb - Rg) + fabsf(wc - Rb2);

        // rgb_left channel-sum > 0 holds w.p. ~1 for uniform(0,255) inputs.
        acc += (wsum > 0.0f) ? diff : 0.0f;
    }

    // wave(64) shuffle reduce, then LDS across 10 waves
    for (int off = 32; off > 0; off >>= 1)
        acc += __shfl_down(acc, off, 64);

    const int lane = threadIdx.x & 63;
    const int wave = threadIdx.x >> 6;
    if (lane == 0) red[wave] = acc;
    __syncthreads();
    if (threadIdx.x == 0) {
        float s = 0.0f;
#pragma unroll
        for (int w = 0; w < NTHREADS / 64; ++w) s += red[w];
        __builtin_nontemporal_store(s, &partials[blockIdx.x]);
    }
}

__global__ __launch_bounds__(1024) void photo_finish(
    const float* __restrict__ partials,
    float* __restrict__ out,
    int nb)
{
    double s = 0.0;
    for (int i = threadIdx.x; i < nb; i += blockDim.x)
        s += (double)partials[i];

    for (int off = 32; off > 0; off >>= 1)
        s += __shfl_down(s, off, 64);

    __shared__ double lds[16];
    const int lane = threadIdx.x & 63;
    const int wave = threadIdx.x >> 6;
    if (lane == 0) lds[wave] = s;
    __syncthreads();
    if (threadIdx.x == 0) {
        double tt = 0.0;
#pragma unroll
        for (int w = 0; w < 16; ++w) tt += lds[w];
        out[0] = (float)(tt / (double)NPIX);
    }
}

extern "C" void kernel_launch(void* const* d_in, const int* in_sizes, int n_in,
                              void* d_out, int out_size, void* d_ws, size_t ws_size,
                              hipStream_t stream) {
    const float* rgb_right = (const float*)d_in[0];
    const float* rgb_left  = (const float*)d_in[1];
    const float* depth     = (const float*)d_in[2];
    float* partials = (float*)d_ws;
    float* out = (float*)d_out;

    photo_main<<<NBLOCKS, NTHREADS, 0, stream>>>(rgb_right, rgb_left, depth, partials);
    photo_finish<<<1, 1024, 0, stream>>>(partials, out, NBLOCKS);
}

// Round 4
// 257.454 us; speedup vs baseline: 1.1593x; 1.0036x over previous
//
#include <hip/hip_runtime.h>

// Problem constants (from reference)
#define IMG_W 640
#define IMG_H 480
#define BATCH 32
#define HWSZ (IMG_H * IMG_W)          // 307200
#define CHWSZ (3 * HWSZ)              // 921600
#define NPIX (BATCH * HWSZ)           // 9830400

// TRAFFIC MODEL (R0-R3): harness re-poisons inputs each iteration, leaving
// ~275 MB dirty in L3. Regular loads evict those lines -> ~240-300 MB
// write-back storm inside our dispatch (R0-R2 all saturated at 3.8 TB/s
// COMBINED R+W). Fix (R3, confirmed: photo_main fell below the 68 us fill
// kernels): __builtin_nontemporal_load on ALL global reads -> no L2/L3
// allocation -> no poison eviction. Cost: zero cache reuse, so all reuse is
// explicit in LDS and staging overdraw comes straight from HBM.
//
// R4: shrink the overdraw. ROWS_PER_BLK 2->4: stage 5 source rows per 4
// output rows (1.25x vs 1.5x) -> reads 334->305 MB. y0(v) = v-1 (v<=239) or
// v (v>=240); 240 % 4 == 0, so each aligned 4-row block needs exactly rows
// y0(v0)..y0(v0)+4 and slot s0 == i for every row (verified both regimes,
// clamped edge rows carry zero weight). LDS 51.2 KB -> 3 blocks/CU, wave-
// capped occupancy unchanged (30/32).

#define ROWS_PER_BLK 4
#define VBLKS_PER_IMG (IMG_H / ROWS_PER_BLK)   // 120
#define NBLOCKS (BATCH * VBLKS_PER_IMG)        // 3840
#define NTHREADS IMG_W                         // 640 threads = 10 waves
#define NROWS_STAGED (ROWS_PER_BLK + 1)        // 5
#define NXCD 8
#define CHUNK (NBLOCKS / NXCD)                 // 480 (= 4 images per XCD)

__global__ __launch_bounds__(NTHREADS) void photo_main(
    const float* __restrict__ rgb_right,
    const float* __restrict__ rgb_left,
    const float* __restrict__ depth,
    float* __restrict__ partials)
{
    // XCD-aware bijective swizzle (NBLOCKS % 8 == 0): blocks sharing an XCD
    // map to a contiguous chunk of work.
    const int bid = blockIdx.x;
    const int wid = (bid & (NXCD - 1)) * CHUNK + (bid >> 3);
    const int bb = wid / VBLKS_PER_IMG;
    const int vblk = wid - bb * VBLKS_PER_IMG;
    const int v0 = ROWS_PER_BLK * vblk;
    const int t = threadIdx.x;          // x coordinate, 0..639

    __shared__ float4 tile[NROWS_STAGED * IMG_W];  // [slot][x] = {r,g,b,0}
    __shared__ float red[NTHREADS / 64];

    const float* __restrict__ Lb = rgb_left + (size_t)bb * CHWSZ;

    // First source row for this block (exact float math; see header comment)
    const float yrow0 = (480.0f * (float)v0) / 479.0f - 0.5f;
    const int y0s0 = (int)floorf(yrow0);

    // Stage 5 source rows x 640 px, packed RGBX. Non-temporal: no L2/L3
    // allocation. Lanes write consecutive x -> ds_write_b128 conflict-free.
#pragma unroll
    for (int k = 0; k < NROWS_STAGED; ++k) {
        const int rsrc = min(max(y0s0 + k, 0), IMG_H - 1);
        const float* src = Lb + (size_t)rsrc * IMG_W + t;
        tile[k * IMG_W + t] = make_float4(
            __builtin_nontemporal_load(src),
            __builtin_nontemporal_load(src + HWSZ),
            __builtin_nontemporal_load(src + 2 * HWSZ),
            0.0f);
    }
    __syncthreads();

    // Issue-early: all per-row streaming loads (depth + rgb_right) up front
    // so their HBM latency overlaps the LDS tap phase.
    float dd[ROWS_PER_BLK], Rr[ROWS_PER_BLK], Rg[ROWS_PER_BLK], Rb2[ROWS_PER_BLK];
#pragma unroll
    for (int i = 0; i < ROWS_PER_BLK; ++i) {
        const int v = v0 + i;
        const size_t pbase = (size_t)bb * HWSZ + (size_t)v * IMG_W + t;
        const size_t cbase = (size_t)bb * CHWSZ + (size_t)v * IMG_W + t;
        dd[i]  = __builtin_nontemporal_load(depth + pbase);
        Rr[i]  = __builtin_nontemporal_load(rgb_right + cbase);
        Rg[i]  = __builtin_nontemporal_load(rgb_right + cbase + HWSZ);
        Rb2[i] = __builtin_nontemporal_load(rgb_right + cbase + 2 * HWSZ);
    }

    const float uf = (float)t;
    float acc = 0.0f;

#pragma unroll
    for (int i = 0; i < ROWS_PER_BLK; ++i) {
        const int v = v0 + i;

        // Row-level y math (V_proj == v exactly in the reference's math):
        // y = 480*v/479 - 0.5, constant across the row.
        const float yrow = (480.0f * (float)v) / 479.0f - 0.5f;
        const int y0i = (int)floorf(yrow);
        const float wy1 = yrow - (float)y0i;
        const float wy0 = 1.0f - wy1;
        const float wy0m = (y0i >= 0) ? wy0 : 0.0f;
        const float wy1m = (y0i + 1 <= IMG_H - 1) ? wy1 : 0.0f;
        int s0 = min(max(y0i - y0s0, 0), ROWS_PER_BLK - 1);  // == i (proven)
        const float4* __restrict__ row0 = &tile[s0 * IMG_W];
        const float4* __restrict__ row1 = &tile[(s0 + 1) * IMG_W];

        // x math: U_proj = u + 80/d (algebraic simplification of
        // FU*(d*Xc+B)/Z + CU with Z=d); x = U_proj*(640/639) - 0.5.
        const float rz = __builtin_amdgcn_rcpf(fmaxf(dd[i], 0.001f));
        const float Up = fmaf(80.0f, rz, uf);
        const bool valid = (Up <= 639.0f);     // Up >= 1 always, so un >= -1
        const float x = fmaf(Up, 640.0f / 639.0f, -0.5f);
        const float x0f = floorf(x);
        const float wx1 = x - x0f;
        const float wx0 = 1.0f - wx1;
        const int x0 = (int)x0f;
        const bool vx1 = (x0 < IMG_W - 1);
        const int e0 = min(max(x0, 0), IMG_W - 1);
        const int e1 = min(x0 + 1, IMG_W - 1);

        const float vm = valid ? 1.0f : 0.0f;
        const float v1m = (valid && vx1) ? 1.0f : 0.0f;
        const float w00 = wy0m * wx0 * vm;
        const float w01 = wy0m * wx1 * v1m;
        const float w10 = wy1m * wx0 * vm;
        const float w11 = wy1m * wx1 * v1m;

        // 4 taps, one ds_read_b128 each (RGB packed)
        const float4 t00 = row0[e0];
        const float4 t01 = row0[e1];
        const float4 t10 = row1[e0];
        const float4 t11 = row1[e1];

        const float wa = w00 * t00.x + w01 * t01.x + w10 * t10.x + w11 * t11.x;
        const float wb = w00 * t00.y + w01 * t01.y + w10 * t10.y + w11 * t11.y;
        const float wc = w00 * t00.z + w01 * t01.z + w10 * t10.z + w11 * t11.z;

        const float wsum = wa + wb + wc;
        const float diff = fabsf(wa - Rr[i]) + fabsf(wb - Rg[i]) + fabsf(wc - Rb2[i]);

        // rgb_left channel-sum > 0 holds w.p. ~1 for uniform(0,255) inputs.
        acc += (wsum > 0.0f) ? diff : 0.0f;
    }

    // wave(64) shuffle reduce, then LDS across 10 waves
    for (int off = 32; off > 0; off >>= 1)
        acc += __shfl_down(acc, off, 64);

    const int lane = threadIdx.x & 63;
    const int wave = threadIdx.x >> 6;
    if (lane == 0) red[wave] = acc;
    __syncthreads();
    if (threadIdx.x == 0) {
        float s = 0.0f;
#pragma unroll
        for (int w = 0; w < NTHREADS / 64; ++w) s += red[w];
        __builtin_nontemporal_store(s, &partials[blockIdx.x]);
    }
}

__global__ __launch_bounds__(1024) void photo_finish(
    const float* __restrict__ partials,
    float* __restrict__ out,
    int nb)
{
    double s = 0.0;
    for (int i = threadIdx.x; i < nb; i += blockDim.x)
        s += (double)partials[i];

    for (int off = 32; off > 0; off >>= 1)
        s += __shfl_down(s, off, 64);

    __shared__ double lds[16];
    const int lane = threadIdx.x & 63;
    const int wave = threadIdx.x >> 6;
    if (lane == 0) lds[wave] = s;
    __syncthreads();
    if (threadIdx.x == 0) {
        double tt = 0.0;
#pragma unroll
        for (int w = 0; w < 16; ++w) tt += lds[w];
        out[0] = (float)(tt / (double)NPIX);
    }
}

extern "C" void kernel_launch(void* const* d_in, const int* in_sizes, int n_in,
                              void* d_out, int out_size, void* d_ws, size_t ws_size,
                              hipStream_t stream) {
    const float* rgb_right = (const float*)d_in[0];
    const float* rgb_left  = (const float*)d_in[1];
    const float* depth     = (const float*)d_in[2];
    float* partials = (float*)d_ws;
    float* out = (float*)d_out;

    photo_main<<<NBLOCKS, NTHREADS, 0, stream>>>(rgb_right, rgb_left, depth, partials);
    photo_finish<<<1, 1024, 0, stream>>>(partials, out, NBLOCKS);
}